// Round 1
// baseline (857.559 us; speedup 1.0000x reference)
//
#include <hip/hip_runtime.h>
#include <hip/hip_bf16.h>

#define N_NODES  100000
#define N_EDGES  1600000
#define N_GRAPHS 1000
#define D        128
#define SCAN_BLOCKS 98   // ceil(100000/1024)

// ---------------- degree / dinv ----------------
__global__ void k_deg(const int* __restrict__ dst, int* __restrict__ cnt) {
    int i = blockIdx.x * 256 + threadIdx.x;
    if (i < N_EDGES) atomicAdd(&cnt[dst[i]], 1);
}

__global__ void k_dinv(const int* __restrict__ cnt, float* __restrict__ dinv) {
    int i = blockIdx.x * 256 + threadIdx.x;
    if (i < N_NODES) dinv[i] = 1.0f / sqrtf((float)cnt[i] + 1.0f);
}

// ---------------- exclusive scan (3-kernel) ----------------
__global__ void k_scan1(const int* __restrict__ cnt, int* __restrict__ out,
                        int* __restrict__ bsum) {
    __shared__ int s[256];
    int t = threadIdx.x;
    int base = blockIdx.x * 1024 + t * 4;
    int v0 = 0, v1 = 0, v2 = 0, v3 = 0;
    if (base + 3 < N_NODES) {
        int4 v = *(const int4*)&cnt[base];
        v0 = v.x; v1 = v.y; v2 = v.z; v3 = v.w;
    } else {
        if (base     < N_NODES) v0 = cnt[base];
        if (base + 1 < N_NODES) v1 = cnt[base + 1];
        if (base + 2 < N_NODES) v2 = cnt[base + 2];
        if (base + 3 < N_NODES) v3 = cnt[base + 3];
    }
    int tsum = v0 + v1 + v2 + v3;
    s[t] = tsum;
    __syncthreads();
    for (int off = 1; off < 256; off <<= 1) {
        int val = (t >= off) ? s[t - off] : 0;
        __syncthreads();
        s[t] += val;
        __syncthreads();
    }
    int excl = s[t] - tsum;
    if (t == 255) bsum[blockIdx.x] = s[255];
    int o0 = excl, o1 = o0 + v0, o2 = o1 + v1, o3 = o2 + v2;
    if (base     < N_NODES) out[base]     = o0;
    if (base + 1 < N_NODES) out[base + 1] = o1;
    if (base + 2 < N_NODES) out[base + 2] = o2;
    if (base + 3 < N_NODES) out[base + 3] = o3;
}

__global__ void k_scan2(int* __restrict__ bsum) {
    __shared__ int s[128];
    int t = threadIdx.x;
    int v = (t < SCAN_BLOCKS) ? bsum[t] : 0;
    s[t] = v;
    __syncthreads();
    for (int off = 1; off < 128; off <<= 1) {
        int val = (t >= off) ? s[t - off] : 0;
        __syncthreads();
        s[t] += val;
        __syncthreads();
    }
    if (t < SCAN_BLOCKS) bsum[t] = s[t] - v;  // exclusive
}

__global__ void k_scan3(int* __restrict__ out, const int* __restrict__ bsum) {
    int t = threadIdx.x;
    int base = blockIdx.x * 1024 + t * 4;
    int add = bsum[blockIdx.x];
    if (base     < N_NODES) out[base]     += add;
    if (base + 1 < N_NODES) out[base + 1] += add;
    if (base + 2 < N_NODES) out[base + 2] += add;
    if (base + 3 < N_NODES) out[base + 3] += add;
    if (blockIdx.x == 0 && t == 0) out[N_NODES] = N_EDGES;
}

// ---------------- CSR fill ----------------
__global__ void k_fill(const int* __restrict__ src, const int* __restrict__ dst,
                       const int* __restrict__ row_off, int* __restrict__ fill,
                       const float* __restrict__ dinv,
                       int* __restrict__ csr_src, float* __restrict__ csr_coef) {
    int i = blockIdx.x * 256 + threadIdx.x;
    if (i < N_EDGES) {
        int s = src[i], d = dst[i];
        int p = row_off[d] + atomicAdd(&fill[d], 1);
        csr_src[p]  = s;
        csr_coef[p] = dinv[s] * dinv[d];
    }
}

// ---------------- embedding + max_norm ----------------
__global__ __launch_bounds__(256) void k_embed(const int* __restrict__ x,
                                               const float* __restrict__ emb,
                                               float* __restrict__ h) {
    int n = blockIdx.x * 4 + (threadIdx.x >> 6);
    int lane = threadIdx.x & 63;
    if (n >= N_NODES) return;
    int xi = x[n];
    float2 v = ((const float2*)(emb + (size_t)xi * D))[lane];
    float ss = v.x * v.x + v.y * v.y;
    #pragma unroll
    for (int off = 32; off; off >>= 1) ss += __shfl_xor(ss, off);
    float nrm = sqrtf(ss);
    float scale = fminf(1.0f, 1.0f / fmaxf(nrm, 1e-7f));
    v.x *= scale; v.y *= scale;
    ((float2*)(h + (size_t)n * D))[lane] = v;
}

// ---------------- fp32 GEMM: C[M,128] = A[M,128] @ W[128,128] ----------------
// 64-row M tile per block, K split into two 64-halves so LDS <= 64KB.
__global__ __launch_bounds__(256) void k_gemm(const float* __restrict__ A,
                                              const float* __restrict__ W,
                                              float* __restrict__ C) {
    __shared__ float Ws[64 * 128];   // 32 KB (K-half of W)
    __shared__ float As[64 * 68];    // 17.4 KB, stride 68 (16B-aligned rows, no 4-way conflicts)
    int t  = threadIdx.x;
    int m0 = blockIdx.x * 64;
    int cg = t & 15, rg = t >> 4;
    int c0 = cg << 2;   // cols c0..c0+3 and c0+64..c0+67
    int r0 = rg << 2;   // rows r0..r0+3
    float acc[4][8];
    #pragma unroll
    for (int r = 0; r < 4; r++)
        #pragma unroll
        for (int c = 0; c < 8; c++) acc[r][c] = 0.f;

    for (int kt = 0; kt < 2; kt++) {
        // stage W K-half: 64x128
        #pragma unroll
        for (int i = 0; i < 8; i++) {
            int idx = t + i * 256;            // 0..2047 float4s
            int r = idx >> 5, c4 = idx & 31;
            *(float4*)&Ws[r * 128 + (c4 << 2)] =
                *(const float4*)&W[(kt * 64 + r) * 128 + (c4 << 2)];
        }
        // stage A tile: 64 rows x 64 cols
        #pragma unroll
        for (int i = 0; i < 4; i++) {
            int idx = t + i * 256;            // 0..1023 float4s
            int r = idx >> 4, c4 = idx & 15;
            int gr = m0 + r;
            float4 v = make_float4(0.f, 0.f, 0.f, 0.f);
            if (gr < N_NODES)
                v = *(const float4*)&A[(size_t)gr * 128 + kt * 64 + (c4 << 2)];
            *(float4*)&As[r * 68 + (c4 << 2)] = v;
        }
        __syncthreads();
        #pragma unroll 4
        for (int k = 0; k < 64; k++) {
            float4 w0 = *(const float4*)&Ws[k * 128 + c0];
            float4 w1 = *(const float4*)&Ws[k * 128 + c0 + 64];
            float a[4];
            a[0] = As[(r0 + 0) * 68 + k];
            a[1] = As[(r0 + 1) * 68 + k];
            a[2] = As[(r0 + 2) * 68 + k];
            a[3] = As[(r0 + 3) * 68 + k];
            #pragma unroll
            for (int r = 0; r < 4; r++) {
                acc[r][0] += a[r] * w0.x; acc[r][1] += a[r] * w0.y;
                acc[r][2] += a[r] * w0.z; acc[r][3] += a[r] * w0.w;
                acc[r][4] += a[r] * w1.x; acc[r][5] += a[r] * w1.y;
                acc[r][6] += a[r] * w1.z; acc[r][7] += a[r] * w1.w;
            }
        }
        __syncthreads();
    }
    #pragma unroll
    for (int r = 0; r < 4; r++) {
        int gr = m0 + r0 + r;
        if (gr < N_NODES) {
            *(float4*)&C[(size_t)gr * 128 + c0] =
                make_float4(acc[r][0], acc[r][1], acc[r][2], acc[r][3]);
            *(float4*)&C[(size_t)gr * 128 + c0 + 64] =
                make_float4(acc[r][4], acc[r][5], acc[r][6], acc[r][7]);
        }
    }
}

// ---------------- aggregation: agg + self + bias + relu ----------------
__global__ __launch_bounds__(256) void k_agg(const float* __restrict__ hw,
                                             float* __restrict__ hout,
                                             const int* __restrict__ row_off,
                                             const int* __restrict__ csr_src,
                                             const float* __restrict__ csr_coef,
                                             const float* __restrict__ dinv,
                                             const float* __restrict__ bias) {
    int n = blockIdx.x * 4 + (threadIdx.x >> 6);
    int lane = threadIdx.x & 63;
    if (n >= N_NODES) return;
    float di = dinv[n];
    float2 self = ((const float2*)(hw + (size_t)n * D))[lane];
    float2 acc;
    acc.x = self.x * di * di;
    acc.y = self.y * di * di;
    int e0 = __builtin_amdgcn_readfirstlane(row_off[n]);
    int e1 = __builtin_amdgcn_readfirstlane(row_off[n + 1]);
    for (int base = e0; base < e1; base += 64) {
        int cnt = min(64, e1 - base);
        int   s_l = 0;
        float c_l = 0.f;
        if (lane < cnt) {
            s_l = csr_src[base + lane];
            c_l = csr_coef[base + lane];
        }
        for (int j = 0; j < cnt; j++) {
            int   s = __shfl(s_l, j);
            float c = __shfl(c_l, j);
            float2 v = ((const float2*)(hw + (size_t)s * D))[lane];
            acc.x += v.x * c;
            acc.y += v.y * c;
        }
    }
    float2 b = ((const float2*)bias)[lane];
    acc.x = fmaxf(acc.x + b.x, 0.f);
    acc.y = fmaxf(acc.y + b.y, 0.f);
    ((float2*)(hout + (size_t)n * D))[lane] = acc;
}

// ---------------- graph boundaries ----------------
__global__ void k_bounds(const int* __restrict__ batch, int* __restrict__ gstart,
                         int* __restrict__ gend) {
    int i = blockIdx.x * 256 + threadIdx.x;
    if (i < N_NODES) {
        int b = batch[i];
        atomicMin(&gstart[b], i);
        atomicMax(&gend[b], i + 1);
    }
}

// ---------------- segment max pool + final linear ----------------
__global__ __launch_bounds__(128) void k_pool(const float* __restrict__ h,
                                              const int* __restrict__ gstart,
                                              const int* __restrict__ gend,
                                              const float* __restrict__ Wf,
                                              const float* __restrict__ bf,
                                              float* __restrict__ out) {
    __shared__ float red[2];
    int g = blockIdx.x;
    int t = threadIdx.x;
    int s = gstart[g], e = gend[g];
    float m = -3.402823466e38f;
    for (int i = s; i < e; i++) m = fmaxf(m, h[(size_t)i * D + t]);
    float val = m * Wf[t];
    #pragma unroll
    for (int off = 32; off; off >>= 1) val += __shfl_xor(val, off);
    if ((t & 63) == 0) red[t >> 6] = val;
    __syncthreads();
    if (t == 0) out[g] = red[0] + red[1] + bf[0];
}

// ---------------- launch ----------------
extern "C" void kernel_launch(void* const* d_in, const int* in_sizes, int n_in,
                              void* d_out, int out_size, void* d_ws, size_t ws_size,
                              hipStream_t stream) {
    const int*   x    = (const int*)d_in[0];
    const int*   ei   = (const int*)d_in[1];   // [2, E]: src row then dst row
    const int*   batch= (const int*)d_in[2];
    const float* emb  = (const float*)d_in[3];
    const float* W1   = (const float*)d_in[4];
    const float* b1   = (const float*)d_in[5];
    const float* W2   = (const float*)d_in[6];
    const float* b2   = (const float*)d_in[7];
    const float* W3   = (const float*)d_in[8];
    const float* b3   = (const float*)d_in[9];
    const float* Wf   = (const float*)d_in[10];
    const float* bf   = (const float*)d_in[11];
    float* out = (float*)d_out;

    const int* src = ei;
    const int* dst = ei + N_EDGES;

    // workspace layout (bytes)
    char* p = (char*)d_ws;
    float* hA       = (float*)p;            p += (size_t)N_NODES * D * 4;   // 51.2 MB
    float* hB       = (float*)p;            p += (size_t)N_NODES * D * 4;   // 51.2 MB
    float* dinv     = (float*)p;            p += (size_t)N_NODES * 4;
    int*   deg_cnt  = (int*)p;              p += (size_t)N_NODES * 4;
    int*   fill_cnt = (int*)p;              p += (size_t)N_NODES * 4;
    int*   gend     = (int*)p;              p += (size_t)N_GRAPHS * 4;
    int*   gstart   = (int*)p;              p += (size_t)N_GRAPHS * 4;
    int*   row_off  = (int*)p;              p += (size_t)(N_NODES + 4) * 4;
    int*   csr_src  = (int*)p;              p += (size_t)N_EDGES * 4;
    float* csr_coef = (float*)p;            p += (size_t)N_EDGES * 4;
    int*   bsum     = (int*)p;              p += 512;

    // zero deg_cnt, fill_cnt, gend (contiguous); gstart -> 0x7f7f7f7f
    hipMemsetAsync(deg_cnt, 0, (size_t)(2 * N_NODES + N_GRAPHS) * 4, stream);
    hipMemsetAsync(gstart, 0x7f, (size_t)N_GRAPHS * 4, stream);

    const int EB = (N_EDGES + 255) / 256;    // 6250
    const int NB = (N_NODES + 255) / 256;    // 391
    const int NW = (N_NODES + 3) / 4;        // 25000 (wave-per-node kernels)
    const int GB = (N_NODES + 63) / 64;      // 1563 (gemm)

    k_deg  <<<EB, 256, 0, stream>>>(dst, deg_cnt);
    k_dinv <<<NB, 256, 0, stream>>>(deg_cnt, dinv);
    k_scan1<<<SCAN_BLOCKS, 256, 0, stream>>>(deg_cnt, row_off, bsum);
    k_scan2<<<1, 128, 0, stream>>>(bsum);
    k_scan3<<<SCAN_BLOCKS, 256, 0, stream>>>(row_off, bsum);
    k_fill <<<EB, 256, 0, stream>>>(src, dst, row_off, fill_cnt, dinv, csr_src, csr_coef);
    k_embed<<<NW, 256, 0, stream>>>(x, emb, hA);

    // layer 1
    k_gemm<<<GB, 256, 0, stream>>>(hA, W1, hB);
    k_agg <<<NW, 256, 0, stream>>>(hB, hA, row_off, csr_src, csr_coef, dinv, b1);
    // layer 2
    k_gemm<<<GB, 256, 0, stream>>>(hA, W2, hB);
    k_agg <<<NW, 256, 0, stream>>>(hB, hA, row_off, csr_src, csr_coef, dinv, b2);
    // layer 3
    k_gemm<<<GB, 256, 0, stream>>>(hA, W3, hB);
    k_agg <<<NW, 256, 0, stream>>>(hB, hA, row_off, csr_src, csr_coef, dinv, b3);

    k_bounds<<<NB, 256, 0, stream>>>(batch, gstart, gend);
    k_pool  <<<N_GRAPHS, 128, 0, stream>>>(hA, gstart, gend, Wf, bf, out);
}

// Round 2
// 842.012 us; speedup vs baseline: 1.0185x; 1.0185x over previous
//
#include <hip/hip_runtime.h>
#include <hip/hip_bf16.h>

#define N_NODES  100000
#define N_EDGES  1600000
#define N_GRAPHS 1000
#define D        128
#define SCAN_BLOCKS 98   // ceil(100000/1024)

// bf16 round-to-nearest-even from fp32 (bit trick, no NaN handling needed here)
__device__ inline unsigned short f2bf(float f) {
    unsigned u = __float_as_uint(f);
    unsigned r = u + 0x7fffu + ((u >> 16) & 1u);
    return (unsigned short)(r >> 16);
}

// ---------------- degree / dinv ----------------
__global__ void k_deg(const int* __restrict__ dst, int* __restrict__ cnt) {
    int i = blockIdx.x * 256 + threadIdx.x;
    if (i < N_EDGES) atomicAdd(&cnt[dst[i]], 1);
}

__global__ void k_dinv(const int* __restrict__ cnt, float* __restrict__ dinv) {
    int i = blockIdx.x * 256 + threadIdx.x;
    if (i < N_NODES) dinv[i] = 1.0f / sqrtf((float)cnt[i] + 1.0f);
}

// ---------------- exclusive scan (3-kernel) ----------------
__global__ void k_scan1(const int* __restrict__ cnt, int* __restrict__ out,
                        int* __restrict__ bsum) {
    __shared__ int s[256];
    int t = threadIdx.x;
    int base = blockIdx.x * 1024 + t * 4;
    int v0 = 0, v1 = 0, v2 = 0, v3 = 0;
    if (base + 3 < N_NODES) {
        int4 v = *(const int4*)&cnt[base];
        v0 = v.x; v1 = v.y; v2 = v.z; v3 = v.w;
    } else {
        if (base     < N_NODES) v0 = cnt[base];
        if (base + 1 < N_NODES) v1 = cnt[base + 1];
        if (base + 2 < N_NODES) v2 = cnt[base + 2];
        if (base + 3 < N_NODES) v3 = cnt[base + 3];
    }
    int tsum = v0 + v1 + v2 + v3;
    s[t] = tsum;
    __syncthreads();
    for (int off = 1; off < 256; off <<= 1) {
        int val = (t >= off) ? s[t - off] : 0;
        __syncthreads();
        s[t] += val;
        __syncthreads();
    }
    int excl = s[t] - tsum;
    if (t == 255) bsum[blockIdx.x] = s[255];
    int o0 = excl, o1 = o0 + v0, o2 = o1 + v1, o3 = o2 + v2;
    if (base     < N_NODES) out[base]     = o0;
    if (base + 1 < N_NODES) out[base + 1] = o1;
    if (base + 2 < N_NODES) out[base + 2] = o2;
    if (base + 3 < N_NODES) out[base + 3] = o3;
}

__global__ void k_scan2(int* __restrict__ bsum) {
    __shared__ int s[128];
    int t = threadIdx.x;
    int v = (t < SCAN_BLOCKS) ? bsum[t] : 0;
    s[t] = v;
    __syncthreads();
    for (int off = 1; off < 128; off <<= 1) {
        int val = (t >= off) ? s[t - off] : 0;
        __syncthreads();
        s[t] += val;
        __syncthreads();
    }
    if (t < SCAN_BLOCKS) bsum[t] = s[t] - v;  // exclusive
}

__global__ void k_scan3(int* __restrict__ out, const int* __restrict__ bsum) {
    int t = threadIdx.x;
    int base = blockIdx.x * 1024 + t * 4;
    int add = bsum[blockIdx.x];
    if (base     < N_NODES) out[base]     += add;
    if (base + 1 < N_NODES) out[base + 1] += add;
    if (base + 2 < N_NODES) out[base + 2] += add;
    if (base + 3 < N_NODES) out[base + 3] += add;
    if (blockIdx.x == 0 && t == 0) out[N_NODES] = N_EDGES;
}

// ---------------- CSR fill ----------------
__global__ void k_fill(const int* __restrict__ src, const int* __restrict__ dst,
                       const int* __restrict__ row_off, int* __restrict__ fill,
                       const float* __restrict__ dinv,
                       int* __restrict__ csr_src, float* __restrict__ csr_coef) {
    int i = blockIdx.x * 256 + threadIdx.x;
    if (i < N_EDGES) {
        int s = src[i], d = dst[i];
        int p = row_off[d] + atomicAdd(&fill[d], 1);
        csr_src[p]  = s;
        csr_coef[p] = dinv[s] * dinv[d];
    }
}

// ---------------- embedding + max_norm ----------------
__global__ __launch_bounds__(256) void k_embed(const int* __restrict__ x,
                                               const float* __restrict__ emb,
                                               float* __restrict__ h) {
    int n = blockIdx.x * 4 + (threadIdx.x >> 6);
    int lane = threadIdx.x & 63;
    if (n >= N_NODES) return;
    int xi = x[n];
    float2 v = ((const float2*)(emb + (size_t)xi * D))[lane];
    float ss = v.x * v.x + v.y * v.y;
    #pragma unroll
    for (int off = 32; off; off >>= 1) ss += __shfl_xor(ss, off);
    float nrm = sqrtf(ss);
    float scale = fminf(1.0f, 1.0f / fmaxf(nrm, 1e-7f));
    v.x *= scale; v.y *= scale;
    ((float2*)(h + (size_t)n * D))[lane] = v;
}

// ---------------- fp32 GEMM: Cb[M,128](bf16) = A[M,128] @ W[128,128] ----------------
// 64-row M tile per block, K split into two 64-halves; output written bf16 only
// (consumed by the bandwidth-bound gather in k_agg; accumulation stays fp32).
__global__ __launch_bounds__(256) void k_gemm(const float* __restrict__ A,
                                              const float* __restrict__ W,
                                              unsigned short* __restrict__ Cb) {
    __shared__ float Ws[64 * 128];   // 32 KB (K-half of W)
    __shared__ float As[64 * 68];    // 17.4 KB, stride 68 (16B-aligned rows, 2-way max bank alias)
    int t  = threadIdx.x;
    int m0 = blockIdx.x * 64;
    int cg = t & 15, rg = t >> 4;
    int c0 = cg << 2;   // cols c0..c0+3 and c0+64..c0+67
    int r0 = rg << 2;   // rows r0..r0+3
    float acc[4][8];
    #pragma unroll
    for (int r = 0; r < 4; r++)
        #pragma unroll
        for (int c = 0; c < 8; c++) acc[r][c] = 0.f;

    for (int kt = 0; kt < 2; kt++) {
        #pragma unroll
        for (int i = 0; i < 8; i++) {
            int idx = t + i * 256;            // 0..2047 float4s
            int r = idx >> 5, c4 = idx & 31;
            *(float4*)&Ws[r * 128 + (c4 << 2)] =
                *(const float4*)&W[(kt * 64 + r) * 128 + (c4 << 2)];
        }
        #pragma unroll
        for (int i = 0; i < 4; i++) {
            int idx = t + i * 256;            // 0..1023 float4s
            int r = idx >> 4, c4 = idx & 15;
            int gr = m0 + r;
            float4 v = make_float4(0.f, 0.f, 0.f, 0.f);
            if (gr < N_NODES)
                v = *(const float4*)&A[(size_t)gr * 128 + kt * 64 + (c4 << 2)];
            *(float4*)&As[r * 68 + (c4 << 2)] = v;
        }
        __syncthreads();
        // k in chunks of 4: 12 ds_read_b128 per 128 FMAs
        #pragma unroll
        for (int k4 = 0; k4 < 16; k4++) {
            float4 a[4];
            #pragma unroll
            for (int r = 0; r < 4; r++)
                a[r] = *(const float4*)&As[(r0 + r) * 68 + (k4 << 2)];
            #pragma unroll
            for (int kk = 0; kk < 4; kk++) {
                int k = (k4 << 2) + kk;
                float4 w0 = *(const float4*)&Ws[k * 128 + c0];
                float4 w1 = *(const float4*)&Ws[k * 128 + c0 + 64];
                #pragma unroll
                for (int r = 0; r < 4; r++) {
                    float av = ((const float*)&a[r])[kk];
                    acc[r][0] += av * w0.x; acc[r][1] += av * w0.y;
                    acc[r][2] += av * w0.z; acc[r][3] += av * w0.w;
                    acc[r][4] += av * w1.x; acc[r][5] += av * w1.y;
                    acc[r][6] += av * w1.z; acc[r][7] += av * w1.w;
                }
            }
        }
        __syncthreads();
    }
    #pragma unroll
    for (int r = 0; r < 4; r++) {
        int gr = m0 + r0 + r;
        if (gr < N_NODES) {
            ushort4 p0 = { f2bf(acc[r][0]), f2bf(acc[r][1]), f2bf(acc[r][2]), f2bf(acc[r][3]) };
            ushort4 p1 = { f2bf(acc[r][4]), f2bf(acc[r][5]), f2bf(acc[r][6]), f2bf(acc[r][7]) };
            *(ushort4*)&Cb[(size_t)gr * 128 + c0]      = p0;
            *(ushort4*)&Cb[(size_t)gr * 128 + c0 + 64] = p1;
        }
    }
}

// ---------------- aggregation: agg + self + bias + relu ----------------
// hw is bf16 (256 B/row gather); accumulation fp32; output fp32.
__global__ __launch_bounds__(256) void k_agg(const unsigned short* __restrict__ hw,
                                             float* __restrict__ hout,
                                             const int* __restrict__ row_off,
                                             const int* __restrict__ csr_src,
                                             const float* __restrict__ csr_coef,
                                             const float* __restrict__ dinv,
                                             const float* __restrict__ bias) {
    int n = blockIdx.x * 4 + (threadIdx.x >> 6);
    int lane = threadIdx.x & 63;
    if (n >= N_NODES) return;
    float di = dinv[n];
    unsigned su = ((const unsigned*)(hw + (size_t)n * D))[lane];
    float sc = di * di;
    float2 acc;
    acc.x = __uint_as_float(su << 16) * sc;           // element 2*lane
    acc.y = __uint_as_float(su & 0xffff0000u) * sc;   // element 2*lane+1
    int e0 = __builtin_amdgcn_readfirstlane(row_off[n]);
    int e1 = __builtin_amdgcn_readfirstlane(row_off[n + 1]);
    for (int base = e0; base < e1; base += 64) {
        int cnt = min(64, e1 - base);
        int   s_l = 0;
        float c_l = 0.f;
        if (lane < cnt) {
            s_l = csr_src[base + lane];
            c_l = csr_coef[base + lane];
        }
        for (int j = 0; j < cnt; j++) {
            int   s = __shfl(s_l, j);
            float c = __shfl(c_l, j);
            unsigned u = ((const unsigned*)(hw + (size_t)s * D))[lane];
            acc.x += __uint_as_float(u << 16) * c;
            acc.y += __uint_as_float(u & 0xffff0000u) * c;
        }
    }
    float2 b = ((const float2*)bias)[lane];
    acc.x = fmaxf(acc.x + b.x, 0.f);
    acc.y = fmaxf(acc.y + b.y, 0.f);
    ((float2*)(hout + (size_t)n * D))[lane] = acc;
}

// ---------------- graph boundaries ----------------
__global__ void k_bounds(const int* __restrict__ batch, int* __restrict__ gstart,
                         int* __restrict__ gend) {
    int i = blockIdx.x * 256 + threadIdx.x;
    if (i < N_NODES) {
        int b = batch[i];
        atomicMin(&gstart[b], i);
        atomicMax(&gend[b], i + 1);
    }
}

// ---------------- segment max pool + final linear ----------------
__global__ __launch_bounds__(128) void k_pool(const float* __restrict__ h,
                                              const int* __restrict__ gstart,
                                              const int* __restrict__ gend,
                                              const float* __restrict__ Wf,
                                              const float* __restrict__ bf,
                                              float* __restrict__ out) {
    __shared__ float red[2];
    int g = blockIdx.x;
    int t = threadIdx.x;
    int s = gstart[g], e = gend[g];
    float m = -3.402823466e38f;
    for (int i = s; i < e; i++) m = fmaxf(m, h[(size_t)i * D + t]);
    float val = m * Wf[t];
    #pragma unroll
    for (int off = 32; off; off >>= 1) val += __shfl_xor(val, off);
    if ((t & 63) == 0) red[t >> 6] = val;
    __syncthreads();
    if (t == 0) out[g] = red[0] + red[1] + bf[0];
}

// ---------------- launch ----------------
extern "C" void kernel_launch(void* const* d_in, const int* in_sizes, int n_in,
                              void* d_out, int out_size, void* d_ws, size_t ws_size,
                              hipStream_t stream) {
    const int*   x    = (const int*)d_in[0];
    const int*   ei   = (const int*)d_in[1];   // [2, E]: src row then dst row
    const int*   batch= (const int*)d_in[2];
    const float* emb  = (const float*)d_in[3];
    const float* W1   = (const float*)d_in[4];
    const float* b1   = (const float*)d_in[5];
    const float* W2   = (const float*)d_in[6];
    const float* b2   = (const float*)d_in[7];
    const float* W3   = (const float*)d_in[8];
    const float* b3   = (const float*)d_in[9];
    const float* Wf   = (const float*)d_in[10];
    const float* bf   = (const float*)d_in[11];
    float* out = (float*)d_out;

    const int* src = ei;
    const int* dst = ei + N_EDGES;

    // workspace layout (bytes)
    char* p = (char*)d_ws;
    float*          hA   = (float*)p;          p += (size_t)N_NODES * D * 4;   // 51.2 MB fp32 h
    unsigned short* hwb  = (unsigned short*)p; p += (size_t)N_NODES * D * 2;   // 25.6 MB bf16 h@W
    float* dinv     = (float*)p;            p += (size_t)N_NODES * 4;
    int*   deg_cnt  = (int*)p;              p += (size_t)N_NODES * 4;
    int*   fill_cnt = (int*)p;              p += (size_t)N_NODES * 4;
    int*   gend     = (int*)p;              p += (size_t)N_GRAPHS * 4;
    int*   gstart   = (int*)p;              p += (size_t)N_GRAPHS * 4;
    int*   row_off  = (int*)p;              p += (size_t)(N_NODES + 4) * 4;
    int*   csr_src  = (int*)p;              p += (size_t)N_EDGES * 4;
    float* csr_coef = (float*)p;            p += (size_t)N_EDGES * 4;
    int*   bsum     = (int*)p;              p += 512;

    // zero deg_cnt, fill_cnt, gend (contiguous); gstart -> 0x7f7f7f7f
    hipMemsetAsync(deg_cnt, 0, (size_t)(2 * N_NODES + N_GRAPHS) * 4, stream);
    hipMemsetAsync(gstart, 0x7f, (size_t)N_GRAPHS * 4, stream);

    const int EB = (N_EDGES + 255) / 256;    // 6250
    const int NB = (N_NODES + 255) / 256;    // 391
    const int NW = (N_NODES + 3) / 4;        // 25000 (wave-per-node kernels)
    const int GB = (N_NODES + 63) / 64;      // 1563 (gemm)

    k_deg  <<<EB, 256, 0, stream>>>(dst, deg_cnt);
    k_dinv <<<NB, 256, 0, stream>>>(deg_cnt, dinv);
    k_scan1<<<SCAN_BLOCKS, 256, 0, stream>>>(deg_cnt, row_off, bsum);
    k_scan2<<<1, 128, 0, stream>>>(bsum);
    k_scan3<<<SCAN_BLOCKS, 256, 0, stream>>>(row_off, bsum);
    k_fill <<<EB, 256, 0, stream>>>(src, dst, row_off, fill_cnt, dinv, csr_src, csr_coef);
    k_embed<<<NW, 256, 0, stream>>>(x, emb, hA);

    // layer 1
    k_gemm<<<GB, 256, 0, stream>>>(hA, W1, hwb);
    k_agg <<<NW, 256, 0, stream>>>(hwb, hA, row_off, csr_src, csr_coef, dinv, b1);
    // layer 2
    k_gemm<<<GB, 256, 0, stream>>>(hA, W2, hwb);
    k_agg <<<NW, 256, 0, stream>>>(hwb, hA, row_off, csr_src, csr_coef, dinv, b2);
    // layer 3
    k_gemm<<<GB, 256, 0, stream>>>(hA, W3, hwb);
    k_agg <<<NW, 256, 0, stream>>>(hwb, hA, row_off, csr_src, csr_coef, dinv, b3);

    k_bounds<<<NB, 256, 0, stream>>>(batch, gstart, gend);
    k_pool  <<<N_GRAPHS, 128, 0, stream>>>(hA, gstart, gend, Wf, bf, out);
}

// Round 3
// 697.441 us; speedup vs baseline: 1.2296x; 1.2073x over previous
//
#include <hip/hip_runtime.h>
#include <hip/hip_bf16.h>

#define N_NODES  100000
#define N_EDGES  1600000
#define N_GRAPHS 1000
#define D        128
#define SCAN_BLOCKS 98   // ceil(100000/1024)

// bf16 round-to-nearest-even from fp32 (bit trick, no NaN handling needed here)
__device__ inline unsigned short f2bf(float f) {
    unsigned u = __float_as_uint(f);
    unsigned r = u + 0x7fffu + ((u >> 16) & 1u);
    return (unsigned short)(r >> 16);
}

// ---------------- degree / dinv ----------------
__global__ void k_deg(const int* __restrict__ dst, int* __restrict__ cnt) {
    int i = blockIdx.x * 256 + threadIdx.x;
    if (i < N_EDGES) atomicAdd(&cnt[dst[i]], 1);
}

__global__ void k_dinv(const int* __restrict__ cnt, float* __restrict__ dinv) {
    int i = blockIdx.x * 256 + threadIdx.x;
    if (i < N_NODES) dinv[i] = 1.0f / sqrtf((float)cnt[i] + 1.0f);
}

// ---------------- exclusive scan (3-kernel) ----------------
__global__ void k_scan1(const int* __restrict__ cnt, int* __restrict__ out,
                        int* __restrict__ bsum) {
    __shared__ int s[256];
    int t = threadIdx.x;
    int base = blockIdx.x * 1024 + t * 4;
    int v0 = 0, v1 = 0, v2 = 0, v3 = 0;
    if (base + 3 < N_NODES) {
        int4 v = *(const int4*)&cnt[base];
        v0 = v.x; v1 = v.y; v2 = v.z; v3 = v.w;
    } else {
        if (base     < N_NODES) v0 = cnt[base];
        if (base + 1 < N_NODES) v1 = cnt[base + 1];
        if (base + 2 < N_NODES) v2 = cnt[base + 2];
        if (base + 3 < N_NODES) v3 = cnt[base + 3];
    }
    int tsum = v0 + v1 + v2 + v3;
    s[t] = tsum;
    __syncthreads();
    for (int off = 1; off < 256; off <<= 1) {
        int val = (t >= off) ? s[t - off] : 0;
        __syncthreads();
        s[t] += val;
        __syncthreads();
    }
    int excl = s[t] - tsum;
    if (t == 255) bsum[blockIdx.x] = s[255];
    int o0 = excl, o1 = o0 + v0, o2 = o1 + v1, o3 = o2 + v2;
    if (base     < N_NODES) out[base]     = o0;
    if (base + 1 < N_NODES) out[base + 1] = o1;
    if (base + 2 < N_NODES) out[base + 2] = o2;
    if (base + 3 < N_NODES) out[base + 3] = o3;
}

__global__ void k_scan2(int* __restrict__ bsum) {
    __shared__ int s[128];
    int t = threadIdx.x;
    int v = (t < SCAN_BLOCKS) ? bsum[t] : 0;
    s[t] = v;
    __syncthreads();
    for (int off = 1; off < 128; off <<= 1) {
        int val = (t >= off) ? s[t - off] : 0;
        __syncthreads();
        s[t] += val;
        __syncthreads();
    }
    if (t < SCAN_BLOCKS) bsum[t] = s[t] - v;  // exclusive
}

__global__ void k_scan3(int* __restrict__ out, const int* __restrict__ bsum) {
    int t = threadIdx.x;
    int base = blockIdx.x * 1024 + t * 4;
    int add = bsum[blockIdx.x];
    if (base     < N_NODES) out[base]     += add;
    if (base + 1 < N_NODES) out[base + 1] += add;
    if (base + 2 < N_NODES) out[base + 2] += add;
    if (base + 3 < N_NODES) out[base + 3] += add;
    if (blockIdx.x == 0 && t == 0) out[N_NODES] = N_EDGES;
}

// ---------------- CSR fill (packed 8B per edge: one dirty line instead of two)
__global__ void k_fill(const int* __restrict__ src, const int* __restrict__ dst,
                       const int* __restrict__ row_off, int* __restrict__ fill,
                       const float* __restrict__ dinv,
                       int2* __restrict__ csr) {
    int i = blockIdx.x * 256 + threadIdx.x;
    if (i < N_EDGES) {
        int s = src[i], d = dst[i];
        int p = row_off[d] + atomicAdd(&fill[d], 1);
        csr[p] = make_int2(s, __float_as_int(dinv[s] * dinv[d]));
    }
}

// ---------------- embedding + max_norm ----------------
__global__ __launch_bounds__(256) void k_embed(const int* __restrict__ x,
                                               const float* __restrict__ emb,
                                               float* __restrict__ h) {
    int n = blockIdx.x * 4 + (threadIdx.x >> 6);
    int lane = threadIdx.x & 63;
    if (n >= N_NODES) return;
    int xi = x[n];
    float2 v = ((const float2*)(emb + (size_t)xi * D))[lane];
    float ss = v.x * v.x + v.y * v.y;
    #pragma unroll
    for (int off = 32; off; off >>= 1) ss += __shfl_xor(ss, off);
    float nrm = sqrtf(ss);
    float scale = fminf(1.0f, 1.0f / fmaxf(nrm, 1e-7f));
    v.x *= scale; v.y *= scale;
    ((float2*)(h + (size_t)n * D))[lane] = v;
}

// ---------------- fp32 GEMM: Cb[M,128](bf16) = A[M,128] @ W[128,128] ----------------
__global__ __launch_bounds__(256) void k_gemm(const float* __restrict__ A,
                                              const float* __restrict__ W,
                                              unsigned short* __restrict__ Cb) {
    __shared__ float Ws[64 * 128];   // 32 KB (K-half of W)
    __shared__ float As[64 * 68];    // 17.4 KB, stride 68
    int t  = threadIdx.x;
    int m0 = blockIdx.x * 64;
    int cg = t & 15, rg = t >> 4;
    int c0 = cg << 2;
    int r0 = rg << 2;
    float acc[4][8];
    #pragma unroll
    for (int r = 0; r < 4; r++)
        #pragma unroll
        for (int c = 0; c < 8; c++) acc[r][c] = 0.f;

    for (int kt = 0; kt < 2; kt++) {
        #pragma unroll
        for (int i = 0; i < 8; i++) {
            int idx = t + i * 256;
            int r = idx >> 5, c4 = idx & 31;
            *(float4*)&Ws[r * 128 + (c4 << 2)] =
                *(const float4*)&W[(kt * 64 + r) * 128 + (c4 << 2)];
        }
        #pragma unroll
        for (int i = 0; i < 4; i++) {
            int idx = t + i * 256;
            int r = idx >> 4, c4 = idx & 15;
            int gr = m0 + r;
            float4 v = make_float4(0.f, 0.f, 0.f, 0.f);
            if (gr < N_NODES)
                v = *(const float4*)&A[(size_t)gr * 128 + kt * 64 + (c4 << 2)];
            *(float4*)&As[r * 68 + (c4 << 2)] = v;
        }
        __syncthreads();
        #pragma unroll
        for (int k4 = 0; k4 < 16; k4++) {
            float4 a[4];
            #pragma unroll
            for (int r = 0; r < 4; r++)
                a[r] = *(const float4*)&As[(r0 + r) * 68 + (k4 << 2)];
            #pragma unroll
            for (int kk = 0; kk < 4; kk++) {
                int k = (k4 << 2) + kk;
                float4 w0 = *(const float4*)&Ws[k * 128 + c0];
                float4 w1 = *(const float4*)&Ws[k * 128 + c0 + 64];
                #pragma unroll
                for (int r = 0; r < 4; r++) {
                    float av = ((const float*)&a[r])[kk];
                    acc[r][0] += av * w0.x; acc[r][1] += av * w0.y;
                    acc[r][2] += av * w0.z; acc[r][3] += av * w0.w;
                    acc[r][4] += av * w1.x; acc[r][5] += av * w1.y;
                    acc[r][6] += av * w1.z; acc[r][7] += av * w1.w;
                }
            }
        }
        __syncthreads();
    }
    #pragma unroll
    for (int r = 0; r < 4; r++) {
        int gr = m0 + r0 + r;
        if (gr < N_NODES) {
            ushort4 p0 = { f2bf(acc[r][0]), f2bf(acc[r][1]), f2bf(acc[r][2]), f2bf(acc[r][3]) };
            ushort4 p1 = { f2bf(acc[r][4]), f2bf(acc[r][5]), f2bf(acc[r][6]), f2bf(acc[r][7]) };
            *(ushort4*)&Cb[(size_t)gr * 128 + c0]      = p0;
            *(ushort4*)&Cb[(size_t)gr * 128 + c0 + 64] = p1;
        }
    }
}

// ---------------- aggregation: agg + self + bias + relu ----------------
// bf16 row gathers, 4 independent loads in flight (latency -> BW bound).
__global__ __launch_bounds__(256) void k_agg(const unsigned short* __restrict__ hw,
                                             float* __restrict__ hout,
                                             const int* __restrict__ row_off,
                                             const int2* __restrict__ csr,
                                             const float* __restrict__ dinv,
                                             const float* __restrict__ bias) {
    int n = blockIdx.x * 4 + (threadIdx.x >> 6);
    int lane = threadIdx.x & 63;
    if (n >= N_NODES) return;
    float di = dinv[n];
    unsigned su = ((const unsigned*)(hw + (size_t)n * D))[lane];
    float sc = di * di;
    float ax = __uint_as_float(su << 16) * sc;
    float ay = __uint_as_float(su & 0xffff0000u) * sc;
    int e0 = __builtin_amdgcn_readfirstlane(row_off[n]);
    int e1 = __builtin_amdgcn_readfirstlane(row_off[n + 1]);
    for (int base = e0; base < e1; base += 64) {
        int cnt = min(64, e1 - base);
        int2 ec = make_int2(0, 0);
        if (lane < cnt) ec = csr[base + lane];
        int j = 0;
        for (; j + 4 <= cnt; j += 4) {
            int s0 = __shfl(ec.x, j + 0);
            int s1 = __shfl(ec.x, j + 1);
            int s2 = __shfl(ec.x, j + 2);
            int s3 = __shfl(ec.x, j + 3);
            float c0 = __uint_as_float((unsigned)__shfl(ec.y, j + 0));
            float c1 = __uint_as_float((unsigned)__shfl(ec.y, j + 1));
            float c2 = __uint_as_float((unsigned)__shfl(ec.y, j + 2));
            float c3 = __uint_as_float((unsigned)__shfl(ec.y, j + 3));
            unsigned u0 = ((const unsigned*)(hw + (size_t)s0 * D))[lane];
            unsigned u1 = ((const unsigned*)(hw + (size_t)s1 * D))[lane];
            unsigned u2 = ((const unsigned*)(hw + (size_t)s2 * D))[lane];
            unsigned u3 = ((const unsigned*)(hw + (size_t)s3 * D))[lane];
            ax += __uint_as_float(u0 << 16) * c0;
            ay += __uint_as_float(u0 & 0xffff0000u) * c0;
            ax += __uint_as_float(u1 << 16) * c1;
            ay += __uint_as_float(u1 & 0xffff0000u) * c1;
            ax += __uint_as_float(u2 << 16) * c2;
            ay += __uint_as_float(u2 & 0xffff0000u) * c2;
            ax += __uint_as_float(u3 << 16) * c3;
            ay += __uint_as_float(u3 & 0xffff0000u) * c3;
        }
        for (; j < cnt; j++) {
            int   s = __shfl(ec.x, j);
            float c = __uint_as_float((unsigned)__shfl(ec.y, j));
            unsigned u = ((const unsigned*)(hw + (size_t)s * D))[lane];
            ax += __uint_as_float(u << 16) * c;
            ay += __uint_as_float(u & 0xffff0000u) * c;
        }
    }
    float2 b = ((const float2*)bias)[lane];
    float2 o;
    o.x = fmaxf(ax + b.x, 0.f);
    o.y = fmaxf(ay + b.y, 0.f);
    ((float2*)(hout + (size_t)n * D))[lane] = o;
}

// ---------------- graph boundaries ----------------
__global__ void k_bounds(const int* __restrict__ batch, int* __restrict__ gstart,
                         int* __restrict__ gend) {
    int i = blockIdx.x * 256 + threadIdx.x;
    if (i < N_NODES) {
        int b = batch[i];
        atomicMin(&gstart[b], i);
        atomicMax(&gend[b], i + 1);
    }
}

// ---------------- segment max pool + final linear (4 waves/graph) ----------------
__global__ __launch_bounds__(256) void k_pool(const float* __restrict__ h,
                                              const int* __restrict__ gstart,
                                              const int* __restrict__ gend,
                                              const float* __restrict__ Wf,
                                              const float* __restrict__ bf,
                                              float* __restrict__ out) {
    __shared__ float2 sm[4][64];
    int g = blockIdx.x;
    int w = threadIdx.x >> 6, lane = threadIdx.x & 63;
    int s = gstart[g], e = gend[g];
    float2 m = make_float2(-3.402823466e38f, -3.402823466e38f);
    for (int i = s + w; i < e; i += 4) {
        float2 v = ((const float2*)(h + (size_t)i * D))[lane];
        m.x = fmaxf(m.x, v.x);
        m.y = fmaxf(m.y, v.y);
    }
    sm[w][lane] = m;
    __syncthreads();
    if (w == 0) {
        float2 a = sm[0][lane], b2 = sm[1][lane], c = sm[2][lane], d = sm[3][lane];
        m.x = fmaxf(fmaxf(a.x, b2.x), fmaxf(c.x, d.x));
        m.y = fmaxf(fmaxf(a.y, b2.y), fmaxf(c.y, d.y));
        float2 wf = ((const float2*)Wf)[lane];
        float val = m.x * wf.x + m.y * wf.y;
        #pragma unroll
        for (int off = 32; off; off >>= 1) val += __shfl_xor(val, off);
        if (lane == 0) out[g] = val + bf[0];
    }
}

// ---------------- launch ----------------
extern "C" void kernel_launch(void* const* d_in, const int* in_sizes, int n_in,
                              void* d_out, int out_size, void* d_ws, size_t ws_size,
                              hipStream_t stream) {
    const int*   x    = (const int*)d_in[0];
    const int*   ei   = (const int*)d_in[1];   // [2, E]: src row then dst row
    const int*   batch= (const int*)d_in[2];
    const float* emb  = (const float*)d_in[3];
    const float* W1   = (const float*)d_in[4];
    const float* b1   = (const float*)d_in[5];
    const float* W2   = (const float*)d_in[6];
    const float* b2   = (const float*)d_in[7];
    const float* W3   = (const float*)d_in[8];
    const float* b3   = (const float*)d_in[9];
    const float* Wf   = (const float*)d_in[10];
    const float* bf   = (const float*)d_in[11];
    float* out = (float*)d_out;

    const int* src = ei;
    const int* dst = ei + N_EDGES;

    // workspace layout (bytes) — all chunks 8B-aligned
    char* p = (char*)d_ws;
    float*          hA   = (float*)p;          p += (size_t)N_NODES * D * 4;   // 51.2 MB
    unsigned short* hwb  = (unsigned short*)p; p += (size_t)N_NODES * D * 2;   // 25.6 MB
    float* dinv     = (float*)p;            p += (size_t)N_NODES * 4;
    int*   deg_cnt  = (int*)p;              p += (size_t)N_NODES * 4;
    int*   fill_cnt = (int*)p;              p += (size_t)N_NODES * 4;
    int*   gend     = (int*)p;              p += (size_t)N_GRAPHS * 4;
    int*   gstart   = (int*)p;              p += (size_t)N_GRAPHS * 4;
    int*   row_off  = (int*)p;              p += (size_t)(N_NODES + 4) * 4;
    int2*  csr      = (int2*)p;             p += (size_t)N_EDGES * 8;          // 12.8 MB
    int*   bsum     = (int*)p;              p += 512;

    // zero deg_cnt, fill_cnt, gend (contiguous); gstart -> 0x7f7f7f7f
    hipMemsetAsync(deg_cnt, 0, (size_t)(2 * N_NODES + N_GRAPHS) * 4, stream);
    hipMemsetAsync(gstart, 0x7f, (size_t)N_GRAPHS * 4, stream);

    const int EB = (N_EDGES + 255) / 256;    // 6250
    const int NB = (N_NODES + 255) / 256;    // 391
    const int NW = (N_NODES + 3) / 4;        // 25000
    const int GB = (N_NODES + 63) / 64;      // 1563

    k_deg  <<<EB, 256, 0, stream>>>(dst, deg_cnt);
    k_dinv <<<NB, 256, 0, stream>>>(deg_cnt, dinv);
    k_scan1<<<SCAN_BLOCKS, 256, 0, stream>>>(deg_cnt, row_off, bsum);
    k_scan2<<<1, 128, 0, stream>>>(bsum);
    k_scan3<<<SCAN_BLOCKS, 256, 0, stream>>>(row_off, bsum);
    k_fill <<<EB, 256, 0, stream>>>(src, dst, row_off, fill_cnt, dinv, csr);
    k_embed<<<NW, 256, 0, stream>>>(x, emb, hA);

    // layer 1
    k_gemm<<<GB, 256, 0, stream>>>(hA, W1, hwb);
    k_agg <<<NW, 256, 0, stream>>>(hwb, hA, row_off, csr, dinv, b1);
    // layer 2
    k_gemm<<<GB, 256, 0, stream>>>(hA, W2, hwb);
    k_agg <<<NW, 256, 0, stream>>>(hwb, hA, row_off, csr, dinv, b2);
    // layer 3
    k_gemm<<<GB, 256, 0, stream>>>(hA, W3, hwb);
    k_agg <<<NW, 256, 0, stream>>>(hwb, hA, row_off, csr, dinv, b3);

    k_bounds<<<NB, 256, 0, stream>>>(batch, gstart, gend);
    k_pool  <<<N_GRAPHS, 256, 0, stream>>>(hA, gstart, gend, Wf, bf, out);
}

// Round 4
// 562.210 us; speedup vs baseline: 1.5253x; 1.2405x over previous
//
#include <hip/hip_runtime.h>
#include <hip/hip_bf16.h>

#define N_NODES  100000
#define N_EDGES  1600000
#define N_GRAPHS 1000
#define D        128
#define SCAN_BLOCKS 98   // ceil(100000/1024)

typedef __attribute__((ext_vector_type(8))) short bf16x8;
typedef __attribute__((ext_vector_type(4))) float f32x4;

__device__ inline f32x4 mfma16(bf16x8 a, bf16x8 b, f32x4 c) {
    return __builtin_amdgcn_mfma_f32_16x16x32_bf16(a, b, c, 0, 0, 0);
}

// bf16 round-to-nearest-even from fp32 (bit trick; inputs here are finite)
__device__ inline unsigned short f2bf(float f) {
    unsigned u = __float_as_uint(f);
    unsigned r = u + 0x7fffu + ((u >> 16) & 1u);
    return (unsigned short)(r >> 16);
}

// ---------------- degree / dinv ----------------
__global__ void k_deg(const int* __restrict__ dst, int* __restrict__ cnt) {
    int i = blockIdx.x * 256 + threadIdx.x;
    if (i < N_EDGES) atomicAdd(&cnt[dst[i]], 1);
}

__global__ void k_dinv(const int* __restrict__ cnt, float* __restrict__ dinv) {
    int i = blockIdx.x * 256 + threadIdx.x;
    if (i < N_NODES) dinv[i] = 1.0f / sqrtf((float)cnt[i] + 1.0f);
}

// ---------------- exclusive scan (3-kernel) ----------------
__global__ void k_scan1(const int* __restrict__ cnt, int* __restrict__ out,
                        int* __restrict__ bsum) {
    __shared__ int s[256];
    int t = threadIdx.x;
    int base = blockIdx.x * 1024 + t * 4;
    int v0 = 0, v1 = 0, v2 = 0, v3 = 0;
    if (base + 3 < N_NODES) {
        int4 v = *(const int4*)&cnt[base];
        v0 = v.x; v1 = v.y; v2 = v.z; v3 = v.w;
    } else {
        if (base     < N_NODES) v0 = cnt[base];
        if (base + 1 < N_NODES) v1 = cnt[base + 1];
        if (base + 2 < N_NODES) v2 = cnt[base + 2];
        if (base + 3 < N_NODES) v3 = cnt[base + 3];
    }
    int tsum = v0 + v1 + v2 + v3;
    s[t] = tsum;
    __syncthreads();
    for (int off = 1; off < 256; off <<= 1) {
        int val = (t >= off) ? s[t - off] : 0;
        __syncthreads();
        s[t] += val;
        __syncthreads();
    }
    int excl = s[t] - tsum;
    if (t == 255) bsum[blockIdx.x] = s[255];
    int o0 = excl, o1 = o0 + v0, o2 = o1 + v1, o3 = o2 + v2;
    if (base     < N_NODES) out[base]     = o0;
    if (base + 1 < N_NODES) out[base + 1] = o1;
    if (base + 2 < N_NODES) out[base + 2] = o2;
    if (base + 3 < N_NODES) out[base + 3] = o3;
}

__global__ void k_scan2(int* __restrict__ bsum) {
    __shared__ int s[128];
    int t = threadIdx.x;
    int v = (t < SCAN_BLOCKS) ? bsum[t] : 0;
    s[t] = v;
    __syncthreads();
    for (int off = 1; off < 128; off <<= 1) {
        int val = (t >= off) ? s[t - off] : 0;
        __syncthreads();
        s[t] += val;
        __syncthreads();
    }
    if (t < SCAN_BLOCKS) bsum[t] = s[t] - v;  // exclusive
}

__global__ void k_scan3(int* __restrict__ out, const int* __restrict__ bsum) {
    int t = threadIdx.x;
    int base = blockIdx.x * 1024 + t * 4;
    int add = bsum[blockIdx.x];
    if (base     < N_NODES) out[base]     += add;
    if (base + 1 < N_NODES) out[base + 1] += add;
    if (base + 2 < N_NODES) out[base + 2] += add;
    if (base + 3 < N_NODES) out[base + 3] += add;
    if (blockIdx.x == 0 && t == 0) out[N_NODES] = N_EDGES;
}

// ---------------- CSR fill (packed 8B per edge) ----------------
__global__ void k_fill(const int* __restrict__ src, const int* __restrict__ dst,
                       const int* __restrict__ row_off, int* __restrict__ fill,
                       const float* __restrict__ dinv,
                       int2* __restrict__ csr) {
    int i = blockIdx.x * 256 + threadIdx.x;
    if (i < N_EDGES) {
        int s = src[i], d = dst[i];
        int p = row_off[d] + atomicAdd(&fill[d], 1);
        csr[p] = make_int2(s, __float_as_int(dinv[s] * dinv[d]));
    }
}

// ---------------- embedding + max_norm -> bf16 ----------------
__global__ __launch_bounds__(256) void k_embed(const int* __restrict__ x,
                                               const float* __restrict__ emb,
                                               unsigned short* __restrict__ h) {
    int n = blockIdx.x * 4 + (threadIdx.x >> 6);
    int lane = threadIdx.x & 63;
    if (n >= N_NODES) return;
    int xi = x[n];
    float2 v = ((const float2*)(emb + (size_t)xi * D))[lane];
    float ss = v.x * v.x + v.y * v.y;
    #pragma unroll
    for (int off = 32; off; off >>= 1) ss += __shfl_xor(ss, off);
    float nrm = sqrtf(ss);
    float scale = fminf(1.0f, 1.0f / fmaxf(nrm, 1e-7f));
    unsigned pk = (unsigned)f2bf(v.x * scale) | ((unsigned)f2bf(v.y * scale) << 16);
    ((unsigned*)(h + (size_t)n * D))[lane] = pk;
}

// ---------------- MFMA GEMM: Cb[M,128](bf16) = A[M,128](bf16) @ W[128,128](fp32)
// W split into bf16 hi+lo fragments in LDS (error ~2^-17: fp32-equivalent for
// this threshold). 4 waves x 32 rows per block; A-frags direct from global.
// acc layout (16x16x32): col=lane&15, row=(lane>>4)*4+reg  [measured m89/m91]
__global__ __launch_bounds__(256) void k_gemm(const unsigned short* __restrict__ A,
                                              const float* __restrict__ W,
                                              unsigned short* __restrict__ Cb) {
    __shared__ short Bh[2048 * 8];   // 32 KB: B-frags of W_hi  [nt(8)][kb(4)][lane(64)]
    __shared__ short Bl[2048 * 8];   // 32 KB: B-frags of W_lo
    int t = threadIdx.x;
    #pragma unroll
    for (int f = 0; f < 8; f++) {
        int id = t + f * 256;                 // 2048 fragment-lanes
        int lane = id & 63, kb = (id >> 6) & 3, nt = id >> 8;
        int k0 = kb * 32 + (lane >> 4) * 8;
        int n  = nt * 16 + (lane & 15);
        bf16x8 vh, vl;
        #pragma unroll
        for (int j = 0; j < 8; j++) {
            float wv = W[(k0 + j) * 128 + n];
            unsigned short hs = f2bf(wv);
            float hf = __uint_as_float((unsigned)hs << 16);
            vh[j] = (short)hs;
            vl[j] = (short)f2bf(wv - hf);
        }
        *(bf16x8*)&Bh[id * 8] = vh;
        *(bf16x8*)&Bl[id * 8] = vl;
    }
    __syncthreads();

    int w = t >> 6, lane = t & 63;
    int quad = lane >> 4, col = lane & 15;
    size_t r0 = (size_t)blockIdx.x * 128 + w * 32;   // rows may overrun; buffers have slack
    f32x4 acc[2][8];
    #pragma unroll
    for (int r = 0; r < 2; r++)
        #pragma unroll
        for (int n = 0; n < 8; n++) acc[r][n] = (f32x4){0.f, 0.f, 0.f, 0.f};

    #pragma unroll
    for (int kb = 0; kb < 4; kb++) {
        bf16x8 a0 = *(const bf16x8*)&A[(r0 + col)      * D + kb * 32 + quad * 8];
        bf16x8 a1 = *(const bf16x8*)&A[(r0 + 16 + col) * D + kb * 32 + quad * 8];
        #pragma unroll
        for (int nt = 0; nt < 8; nt++) {
            bf16x8 bh = *(const bf16x8*)&Bh[((nt * 4 + kb) * 64 + lane) * 8];
            bf16x8 bl = *(const bf16x8*)&Bl[((nt * 4 + kb) * 64 + lane) * 8];
            acc[0][nt] = mfma16(a0, bh, acc[0][nt]);
            acc[0][nt] = mfma16(a0, bl, acc[0][nt]);
            acc[1][nt] = mfma16(a1, bh, acc[1][nt]);
            acc[1][nt] = mfma16(a1, bl, acc[1][nt]);
        }
    }
    #pragma unroll
    for (int r = 0; r < 2; r++) {
        size_t row = r0 + r * 16 + quad * 4;
        #pragma unroll
        for (int nt = 0; nt < 8; nt++)
            #pragma unroll
            for (int g = 0; g < 4; g++)
                Cb[(row + g) * D + nt * 16 + col] = f2bf(acc[r][nt][g]);
    }
}

// ---------------- aggregation: agg + self + bias + relu ----------------
// bf16 row gathers, 4 loads in flight; output bf16 (layers 1-2) or fp32 (layer 3).
template<int BF16OUT>
__global__ __launch_bounds__(256) void k_agg(const unsigned short* __restrict__ hw,
                                             void* __restrict__ hout,
                                             const int* __restrict__ row_off,
                                             const int2* __restrict__ csr,
                                             const float* __restrict__ dinv,
                                             const float* __restrict__ bias) {
    int n = blockIdx.x * 4 + (threadIdx.x >> 6);
    int lane = threadIdx.x & 63;
    if (n >= N_NODES) return;
    float di = dinv[n];
    unsigned su = ((const unsigned*)(hw + (size_t)n * D))[lane];
    float sc = di * di;
    float ax = __uint_as_float(su << 16) * sc;
    float ay = __uint_as_float(su & 0xffff0000u) * sc;
    int e0 = __builtin_amdgcn_readfirstlane(row_off[n]);
    int e1 = __builtin_amdgcn_readfirstlane(row_off[n + 1]);
    for (int base = e0; base < e1; base += 64) {
        int cnt = min(64, e1 - base);
        int2 ec = make_int2(0, 0);
        if (lane < cnt) ec = csr[base + lane];
        int j = 0;
        for (; j + 4 <= cnt; j += 4) {
            int s0 = __shfl(ec.x, j + 0);
            int s1 = __shfl(ec.x, j + 1);
            int s2 = __shfl(ec.x, j + 2);
            int s3 = __shfl(ec.x, j + 3);
            float c0 = __uint_as_float((unsigned)__shfl(ec.y, j + 0));
            float c1 = __uint_as_float((unsigned)__shfl(ec.y, j + 1));
            float c2 = __uint_as_float((unsigned)__shfl(ec.y, j + 2));
            float c3 = __uint_as_float((unsigned)__shfl(ec.y, j + 3));
            unsigned u0 = ((const unsigned*)(hw + (size_t)s0 * D))[lane];
            unsigned u1 = ((const unsigned*)(hw + (size_t)s1 * D))[lane];
            unsigned u2 = ((const unsigned*)(hw + (size_t)s2 * D))[lane];
            unsigned u3 = ((const unsigned*)(hw + (size_t)s3 * D))[lane];
            ax += __uint_as_float(u0 << 16) * c0;
            ay += __uint_as_float(u0 & 0xffff0000u) * c0;
            ax += __uint_as_float(u1 << 16) * c1;
            ay += __uint_as_float(u1 & 0xffff0000u) * c1;
            ax += __uint_as_float(u2 << 16) * c2;
            ay += __uint_as_float(u2 & 0xffff0000u) * c2;
            ax += __uint_as_float(u3 << 16) * c3;
            ay += __uint_as_float(u3 & 0xffff0000u) * c3;
        }
        for (; j < cnt; j++) {
            int   s = __shfl(ec.x, j);
            float c = __uint_as_float((unsigned)__shfl(ec.y, j));
            unsigned u = ((const unsigned*)(hw + (size_t)s * D))[lane];
            ax += __uint_as_float(u << 16) * c;
            ay += __uint_as_float(u & 0xffff0000u) * c;
        }
    }
    float2 b = ((const float2*)bias)[lane];
    float ox = fmaxf(ax + b.x, 0.f);
    float oy = fmaxf(ay + b.y, 0.f);
    if (BF16OUT) {
        unsigned pk = (unsigned)f2bf(ox) | ((unsigned)f2bf(oy) << 16);
        ((unsigned*)((unsigned short*)hout + (size_t)n * D))[lane] = pk;
    } else {
        ((float2*)((float*)hout + (size_t)n * D))[lane] = make_float2(ox, oy);
    }
}

// ---------------- graph boundaries ----------------
__global__ void k_bounds(const int* __restrict__ batch, int* __restrict__ gstart,
                         int* __restrict__ gend) {
    int i = blockIdx.x * 256 + threadIdx.x;
    if (i < N_NODES) {
        int b = batch[i];
        atomicMin(&gstart[b], i);
        atomicMax(&gend[b], i + 1);
    }
}

// ---------------- segment max pool + final linear (4 waves/graph) ----------------
__global__ __launch_bounds__(256) void k_pool(const float* __restrict__ h,
                                              const int* __restrict__ gstart,
                                              const int* __restrict__ gend,
                                              const float* __restrict__ Wf,
                                              const float* __restrict__ bf,
                                              float* __restrict__ out) {
    __shared__ float2 sm[4][64];
    int g = blockIdx.x;
    int w = threadIdx.x >> 6, lane = threadIdx.x & 63;
    int s = gstart[g], e = gend[g];
    float2 m = make_float2(-3.402823466e38f, -3.402823466e38f);
    for (int i = s + w; i < e; i += 4) {
        float2 v = ((const float2*)(h + (size_t)i * D))[lane];
        m.x = fmaxf(m.x, v.x);
        m.y = fmaxf(m.y, v.y);
    }
    sm[w][lane] = m;
    __syncthreads();
    if (w == 0) {
        float2 a = sm[0][lane], b2 = sm[1][lane], c = sm[2][lane], d = sm[3][lane];
        m.x = fmaxf(fmaxf(a.x, b2.x), fmaxf(c.x, d.x));
        m.y = fmaxf(fmaxf(a.y, b2.y), fmaxf(c.y, d.y));
        float2 wf = ((const float2*)Wf)[lane];
        float val = m.x * wf.x + m.y * wf.y;
        #pragma unroll
        for (int off = 32; off; off >>= 1) val += __shfl_xor(val, off);
        if (lane == 0) out[g] = val + bf[0];
    }
}

// ---------------- launch ----------------
extern "C" void kernel_launch(void* const* d_in, const int* in_sizes, int n_in,
                              void* d_out, int out_size, void* d_ws, size_t ws_size,
                              hipStream_t stream) {
    const int*   x    = (const int*)d_in[0];
    const int*   ei   = (const int*)d_in[1];   // [2, E]: src row then dst row
    const int*   batch= (const int*)d_in[2];
    const float* emb  = (const float*)d_in[3];
    const float* W1   = (const float*)d_in[4];
    const float* b1   = (const float*)d_in[5];
    const float* W2   = (const float*)d_in[6];
    const float* b2   = (const float*)d_in[7];
    const float* W3   = (const float*)d_in[8];
    const float* b3   = (const float*)d_in[9];
    const float* Wf   = (const float*)d_in[10];
    const float* bf   = (const float*)d_in[11];
    float* out = (float*)d_out;

    const int* src = ei;
    const int* dst = ei + N_EDGES;

    // workspace layout (bytes) — all chunks 16B-aligned.
    // hAb (bf16 feature chain) ALIASES hA's fp32 buffer: hAb is read last by
    // layer-3 gemm, which precedes layer-3 agg's fp32 write of hA. Both have
    // 128 rows of slack for the gemm's 128-row tiles (reads/writes of rows
    // >= N_NODES land in slack, never faulting or clobbering other arrays).
    char* p = (char*)d_ws;
    float*          hA   = (float*)p;          p += (size_t)(N_NODES + 128) * D * 4; // 51.3 MB
    unsigned short* hAb  = (unsigned short*)hA;                                      // alias
    unsigned short* hwb  = (unsigned short*)p; p += (size_t)(N_NODES + 128) * D * 2; // 25.7 MB
    float* dinv     = (float*)p;            p += (size_t)N_NODES * 4;
    int*   deg_cnt  = (int*)p;              p += (size_t)N_NODES * 4;
    int*   fill_cnt = (int*)p;              p += (size_t)N_NODES * 4;
    int*   gend     = (int*)p;              p += (size_t)N_GRAPHS * 4;
    int*   gstart   = (int*)p;              p += (size_t)N_GRAPHS * 4;
    int*   row_off  = (int*)p;              p += (size_t)(N_NODES + 4) * 4;
    int2*  csr      = (int2*)p;             p += (size_t)N_EDGES * 8;               // 12.8 MB
    int*   bsum     = (int*)p;              p += 512;

    hipMemsetAsync(deg_cnt, 0, (size_t)(2 * N_NODES + N_GRAPHS) * 4, stream);
    hipMemsetAsync(gstart, 0x7f, (size_t)N_GRAPHS * 4, stream);

    const int EB = (N_EDGES + 255) / 256;    // 6250
    const int NB = (N_NODES + 255) / 256;    // 391
    const int NW = (N_NODES + 3) / 4;        // 25000
    const int GB = (N_NODES + 127) / 128;    // 782 (mfma gemm)

    k_deg  <<<EB, 256, 0, stream>>>(dst, deg_cnt);
    k_dinv <<<NB, 256, 0, stream>>>(deg_cnt, dinv);
    k_scan1<<<SCAN_BLOCKS, 256, 0, stream>>>(deg_cnt, row_off, bsum);
    k_scan2<<<1, 128, 0, stream>>>(bsum);
    k_scan3<<<SCAN_BLOCKS, 256, 0, stream>>>(row_off, bsum);
    k_fill <<<EB, 256, 0, stream>>>(src, dst, row_off, fill_cnt, dinv, csr);
    k_embed<<<NW, 256, 0, stream>>>(x, emb, hAb);

    // layer 1
    k_gemm  <<<GB, 256, 0, stream>>>(hAb, W1, hwb);
    k_agg<1><<<NW, 256, 0, stream>>>(hwb, hAb, row_off, csr, dinv, b1);
    // layer 2
    k_gemm  <<<GB, 256, 0, stream>>>(hAb, W2, hwb);
    k_agg<1><<<NW, 256, 0, stream>>>(hwb, hAb, row_off, csr, dinv, b2);
    // layer 3
    k_gemm  <<<GB, 256, 0, stream>>>(hAb, W3, hwb);
    k_agg<0><<<NW, 256, 0, stream>>>(hwb, hA, row_off, csr, dinv, b3);

    k_bounds<<<NB, 256, 0, stream>>>(batch, gstart, gend);
    k_pool  <<<N_GRAPHS, 256, 0, stream>>>(hA, gstart, gend, Wf, bf, out);
}

// Round 5
// 507.092 us; speedup vs baseline: 1.6911x; 1.1087x over previous
//
#include <hip/hip_runtime.h>
#include <hip/hip_bf16.h>

#define N_NODES  100000
#define N_EDGES  1600000
#define N_GRAPHS 1000
#define D        128
#define SCAN_BLOCKS 98   // ceil(100000/1024)

typedef __attribute__((ext_vector_type(8))) short bf16x8;
typedef __attribute__((ext_vector_type(4))) float f32x4;

__device__ inline f32x4 mfma16(bf16x8 a, bf16x8 b, f32x4 c) {
    return __builtin_amdgcn_mfma_f32_16x16x32_bf16(a, b, c, 0, 0, 0);
}

// bf16 round-to-nearest-even from fp32 (bit trick; inputs here are finite)
__device__ inline unsigned short f2bf(float f) {
    unsigned u = __float_as_uint(f);
    unsigned r = u + 0x7fffu + ((u >> 16) & 1u);
    return (unsigned short)(r >> 16);
}

// ---------------- degree (also records per-edge rank within dst bucket) -----
__global__ void k_deg(const int* __restrict__ dst, int* __restrict__ cnt,
                      int* __restrict__ rank) {
    int i = blockIdx.x * 256 + threadIdx.x;
    if (i < N_EDGES) rank[i] = atomicAdd(&cnt[dst[i]], 1);
}

// ---------------- exclusive scan (3-kernel); scan1 also emits dinv ----------
__global__ void k_scan1(const int* __restrict__ cnt, int* __restrict__ out,
                        int* __restrict__ bsum, float* __restrict__ dinv) {
    __shared__ int s[256];
    int t = threadIdx.x;
    int base = blockIdx.x * 1024 + t * 4;
    int v0 = 0, v1 = 0, v2 = 0, v3 = 0;
    if (base + 3 < N_NODES) {
        int4 v = *(const int4*)&cnt[base];
        v0 = v.x; v1 = v.y; v2 = v.z; v3 = v.w;
    } else {
        if (base     < N_NODES) v0 = cnt[base];
        if (base + 1 < N_NODES) v1 = cnt[base + 1];
        if (base + 2 < N_NODES) v2 = cnt[base + 2];
        if (base + 3 < N_NODES) v3 = cnt[base + 3];
    }
    if (base + 3 < N_NODES) {
        float4 dv = make_float4(1.0f / sqrtf((float)v0 + 1.0f),
                                1.0f / sqrtf((float)v1 + 1.0f),
                                1.0f / sqrtf((float)v2 + 1.0f),
                                1.0f / sqrtf((float)v3 + 1.0f));
        *(float4*)&dinv[base] = dv;
    } else {
        if (base     < N_NODES) dinv[base]     = 1.0f / sqrtf((float)v0 + 1.0f);
        if (base + 1 < N_NODES) dinv[base + 1] = 1.0f / sqrtf((float)v1 + 1.0f);
        if (base + 2 < N_NODES) dinv[base + 2] = 1.0f / sqrtf((float)v2 + 1.0f);
        if (base + 3 < N_NODES) dinv[base + 3] = 1.0f / sqrtf((float)v3 + 1.0f);
    }
    int tsum = v0 + v1 + v2 + v3;
    s[t] = tsum;
    __syncthreads();
    for (int off = 1; off < 256; off <<= 1) {
        int val = (t >= off) ? s[t - off] : 0;
        __syncthreads();
        s[t] += val;
        __syncthreads();
    }
    int excl = s[t] - tsum;
    if (t == 255) bsum[blockIdx.x] = s[255];
    int o0 = excl, o1 = o0 + v0, o2 = o1 + v1, o3 = o2 + v2;
    if (base     < N_NODES) out[base]     = o0;
    if (base + 1 < N_NODES) out[base + 1] = o1;
    if (base + 2 < N_NODES) out[base + 2] = o2;
    if (base + 3 < N_NODES) out[base + 3] = o3;
}

__global__ void k_scan2(int* __restrict__ bsum) {
    __shared__ int s[128];
    int t = threadIdx.x;
    int v = (t < SCAN_BLOCKS) ? bsum[t] : 0;
    s[t] = v;
    __syncthreads();
    for (int off = 1; off < 128; off <<= 1) {
        int val = (t >= off) ? s[t - off] : 0;
        __syncthreads();
        s[t] += val;
        __syncthreads();
    }
    if (t < SCAN_BLOCKS) bsum[t] = s[t] - v;  // exclusive
}

__global__ void k_scan3(int* __restrict__ out, const int* __restrict__ bsum) {
    int t = threadIdx.x;
    int base = blockIdx.x * 1024 + t * 4;
    int add = bsum[blockIdx.x];
    if (base     < N_NODES) out[base]     += add;
    if (base + 1 < N_NODES) out[base + 1] += add;
    if (base + 2 < N_NODES) out[base + 2] += add;
    if (base + 3 < N_NODES) out[base + 3] += add;
    if (blockIdx.x == 0 && t == 0) out[N_NODES] = N_EDGES;
}

// ---------------- CSR fill (no atomics: rank precomputed in k_deg) ----------
__global__ void k_fill(const int* __restrict__ src, const int* __restrict__ dst,
                       const int* __restrict__ row_off, const int* __restrict__ rank,
                       const float* __restrict__ dinv, int2* __restrict__ csr) {
    int i = blockIdx.x * 256 + threadIdx.x;
    if (i < N_EDGES) {
        int s = src[i], d = dst[i];
        int p = row_off[d] + rank[i];
        csr[p] = make_int2(s, __float_as_int(dinv[s] * dinv[d]));
    }
}

// ---------------- embedding + max_norm -> bf16 ----------------
__global__ __launch_bounds__(256) void k_embed(const int* __restrict__ x,
                                               const float* __restrict__ emb,
                                               unsigned short* __restrict__ h) {
    int n = blockIdx.x * 4 + (threadIdx.x >> 6);
    int lane = threadIdx.x & 63;
    if (n >= N_NODES) return;
    int xi = x[n];
    float2 v = ((const float2*)(emb + (size_t)xi * D))[lane];
    float ss = v.x * v.x + v.y * v.y;
    #pragma unroll
    for (int off = 32; off; off >>= 1) ss += __shfl_xor(ss, off);
    float nrm = sqrtf(ss);
    float scale = fminf(1.0f, 1.0f / fmaxf(nrm, 1e-7f));
    unsigned pk = (unsigned)f2bf(v.x * scale) | ((unsigned)f2bf(v.y * scale) << 16);
    ((unsigned*)(h + (size_t)n * D))[lane] = pk;
}

// ---------------- MFMA GEMM: Cb[M,128](bf16) = A[M,128](bf16) @ W[128,128](fp32)
// W split into bf16 hi+lo fragments in LDS. 4 waves x 32 rows per block.
__global__ __launch_bounds__(256) void k_gemm(const unsigned short* __restrict__ A,
                                              const float* __restrict__ W,
                                              unsigned short* __restrict__ Cb) {
    __shared__ short Bh[2048 * 8];   // 32 KB: B-frags of W_hi
    __shared__ short Bl[2048 * 8];   // 32 KB: B-frags of W_lo
    int t = threadIdx.x;
    #pragma unroll
    for (int f = 0; f < 8; f++) {
        int id = t + f * 256;
        int lane = id & 63, kb = (id >> 6) & 3, nt = id >> 8;
        int k0 = kb * 32 + (lane >> 4) * 8;
        int n  = nt * 16 + (lane & 15);
        bf16x8 vh, vl;
        #pragma unroll
        for (int j = 0; j < 8; j++) {
            float wv = W[(k0 + j) * 128 + n];
            unsigned short hs = f2bf(wv);
            float hf = __uint_as_float((unsigned)hs << 16);
            vh[j] = (short)hs;
            vl[j] = (short)f2bf(wv - hf);
        }
        *(bf16x8*)&Bh[id * 8] = vh;
        *(bf16x8*)&Bl[id * 8] = vl;
    }
    __syncthreads();

    int w = t >> 6, lane = t & 63;
    int quad = lane >> 4, col = lane & 15;
    size_t r0 = (size_t)blockIdx.x * 128 + w * 32;   // buffers have row slack
    f32x4 acc[2][8];
    #pragma unroll
    for (int r = 0; r < 2; r++)
        #pragma unroll
        for (int n = 0; n < 8; n++) acc[r][n] = (f32x4){0.f, 0.f, 0.f, 0.f};

    #pragma unroll
    for (int kb = 0; kb < 4; kb++) {
        bf16x8 a0 = *(const bf16x8*)&A[(r0 + col)      * D + kb * 32 + quad * 8];
        bf16x8 a1 = *(const bf16x8*)&A[(r0 + 16 + col) * D + kb * 32 + quad * 8];
        #pragma unroll
        for (int nt = 0; nt < 8; nt++) {
            bf16x8 bh = *(const bf16x8*)&Bh[((nt * 4 + kb) * 64 + lane) * 8];
            bf16x8 bl = *(const bf16x8*)&Bl[((nt * 4 + kb) * 64 + lane) * 8];
            acc[0][nt] = mfma16(a0, bh, acc[0][nt]);
            acc[0][nt] = mfma16(a0, bl, acc[0][nt]);
            acc[1][nt] = mfma16(a1, bh, acc[1][nt]);
            acc[1][nt] = mfma16(a1, bl, acc[1][nt]);
        }
    }
    #pragma unroll
    for (int r = 0; r < 2; r++) {
        size_t row = r0 + r * 16 + quad * 4;
        #pragma unroll
        for (int nt = 0; nt < 8; nt++)
            #pragma unroll
            for (int g = 0; g < 4; g++)
                Cb[(row + g) * D + nt * 16 + col] = f2bf(acc[r][nt][g]);
    }
}

// ---------------- aggregation: agg + self + bias + relu ----------------
// One wave per node. quad (lane>>4) owns one edge of each group of 4; the 16
// sublanes cover the 256 B bf16 row with int4 loads -> 1 instruction gathers
// 4 rows; unroll x4 -> 16 rows in flight. Lanes >= cnt hold (src 0, coef 0).
__device__ inline void acc8(float* acc, int4 r, float c) {
    unsigned u0 = (unsigned)r.x, u1 = (unsigned)r.y,
             u2 = (unsigned)r.z, u3 = (unsigned)r.w;
    acc[0] += __uint_as_float(u0 << 16) * c;
    acc[1] += __uint_as_float(u0 & 0xffff0000u) * c;
    acc[2] += __uint_as_float(u1 << 16) * c;
    acc[3] += __uint_as_float(u1 & 0xffff0000u) * c;
    acc[4] += __uint_as_float(u2 << 16) * c;
    acc[5] += __uint_as_float(u2 & 0xffff0000u) * c;
    acc[6] += __uint_as_float(u3 << 16) * c;
    acc[7] += __uint_as_float(u3 & 0xffff0000u) * c;
}

template<int BF16OUT>
__global__ __launch_bounds__(256) void k_agg(const unsigned short* __restrict__ hw,
                                             void* __restrict__ hout,
                                             const int* __restrict__ row_off,
                                             const int2* __restrict__ csr,
                                             const float* __restrict__ dinv,
                                             const float* __restrict__ bias) {
    int n = blockIdx.x * 4 + (threadIdx.x >> 6);
    int lane = threadIdx.x & 63;
    if (n >= N_NODES) return;
    int quad = lane >> 4;
    int l16  = lane & 15;          // columns l16*8 .. l16*8+7
    float acc[8];
    #pragma unroll
    for (int c = 0; c < 8; c++) acc[c] = 0.f;

    int e0 = __builtin_amdgcn_readfirstlane(row_off[n]);
    int e1 = __builtin_amdgcn_readfirstlane(row_off[n + 1]);
    for (int base = e0; base < e1; base += 64) {
        int cnt = min(64, e1 - base);
        int2 ec = make_int2(0, 0);             // src 0 / coef 0 for idle lanes
        if (lane < cnt) ec = csr[base + lane];
        for (int j = 0; j < cnt; j += 16) {
            int   s0 = __shfl(ec.x, j + quad);
            int   s1 = __shfl(ec.x, j + 4  + quad);
            int   s2 = __shfl(ec.x, j + 8  + quad);
            int   s3 = __shfl(ec.x, j + 12 + quad);
            float c0 = __uint_as_float((unsigned)__shfl(ec.y, j + quad));
            float c1 = __uint_as_float((unsigned)__shfl(ec.y, j + 4  + quad));
            float c2 = __uint_as_float((unsigned)__shfl(ec.y, j + 8  + quad));
            float c3 = __uint_as_float((unsigned)__shfl(ec.y, j + 12 + quad));
            int4 r0 = *(const int4*)&hw[(size_t)s0 * D + l16 * 8];
            int4 r1 = *(const int4*)&hw[(size_t)s1 * D + l16 * 8];
            int4 r2 = *(const int4*)&hw[(size_t)s2 * D + l16 * 8];
            int4 r3 = *(const int4*)&hw[(size_t)s3 * D + l16 * 8];
            acc8(acc, r0, c0);
            acc8(acc, r1, c1);
            acc8(acc, r2, c2);
            acc8(acc, r3, c3);
        }
    }
    // lanes sharing l16 across the 4 quads hold the same columns: reduce.
    #pragma unroll
    for (int c = 0; c < 8; c++) {
        acc[c] += __shfl_xor(acc[c], 16);
        acc[c] += __shfl_xor(acc[c], 32);
    }
    if (quad == 0) {
        float di = dinv[n], sc = di * di;
        int4 sr = *(const int4*)&hw[(size_t)n * D + l16 * 8];
        float self[8];
        {
            unsigned u0 = (unsigned)sr.x, u1 = (unsigned)sr.y,
                     u2 = (unsigned)sr.z, u3 = (unsigned)sr.w;
            self[0] = __uint_as_float(u0 << 16);
            self[1] = __uint_as_float(u0 & 0xffff0000u);
            self[2] = __uint_as_float(u1 << 16);
            self[3] = __uint_as_float(u1 & 0xffff0000u);
            self[4] = __uint_as_float(u2 << 16);
            self[5] = __uint_as_float(u2 & 0xffff0000u);
            self[6] = __uint_as_float(u3 << 16);
            self[7] = __uint_as_float(u3 & 0xffff0000u);
        }
        float4 bA = *(const float4*)&bias[l16 * 8];
        float4 bB = *(const float4*)&bias[l16 * 8 + 4];
        float o[8];
        o[0] = fmaxf(acc[0] + self[0] * sc + bA.x, 0.f);
        o[1] = fmaxf(acc[1] + self[1] * sc + bA.y, 0.f);
        o[2] = fmaxf(acc[2] + self[2] * sc + bA.z, 0.f);
        o[3] = fmaxf(acc[3] + self[3] * sc + bA.w, 0.f);
        o[4] = fmaxf(acc[4] + self[4] * sc + bB.x, 0.f);
        o[5] = fmaxf(acc[5] + self[5] * sc + bB.y, 0.f);
        o[6] = fmaxf(acc[6] + self[6] * sc + bB.z, 0.f);
        o[7] = fmaxf(acc[7] + self[7] * sc + bB.w, 0.f);
        if (BF16OUT) {
            int4 pk;
            pk.x = (int)((unsigned)f2bf(o[0]) | ((unsigned)f2bf(o[1]) << 16));
            pk.y = (int)((unsigned)f2bf(o[2]) | ((unsigned)f2bf(o[3]) << 16));
            pk.z = (int)((unsigned)f2bf(o[4]) | ((unsigned)f2bf(o[5]) << 16));
            pk.w = (int)((unsigned)f2bf(o[6]) | ((unsigned)f2bf(o[7]) << 16));
            *(int4*)&((unsigned short*)hout)[(size_t)n * D + l16 * 8] = pk;
        } else {
            float* orow = (float*)hout + (size_t)n * D + l16 * 8;
            *(float4*)orow       = make_float4(o[0], o[1], o[2], o[3]);
            *(float4*)(orow + 4) = make_float4(o[4], o[5], o[6], o[7]);
        }
    }
}

// ---------------- graph boundaries ----------------
__global__ void k_bounds(const int* __restrict__ batch, int* __restrict__ gstart,
                         int* __restrict__ gend) {
    int i = blockIdx.x * 256 + threadIdx.x;
    if (i < N_NODES) {
        int b = batch[i];
        atomicMin(&gstart[b], i);
        atomicMax(&gend[b], i + 1);
    }
}

// ---------------- segment max pool + final linear (4 waves/graph) ----------------
__global__ __launch_bounds__(256) void k_pool(const float* __restrict__ h,
                                              const int* __restrict__ gstart,
                                              const int* __restrict__ gend,
                                              const float* __restrict__ Wf,
                                              const float* __restrict__ bf,
                                              float* __restrict__ out) {
    __shared__ float2 sm[4][64];
    int g = blockIdx.x;
    int w = threadIdx.x >> 6, lane = threadIdx.x & 63;
    int s = gstart[g], e = gend[g];
    float2 m = make_float2(-3.402823466e38f, -3.402823466e38f);
    for (int i = s + w; i < e; i += 4) {
        float2 v = ((const float2*)(h + (size_t)i * D))[lane];
        m.x = fmaxf(m.x, v.x);
        m.y = fmaxf(m.y, v.y);
    }
    sm[w][lane] = m;
    __syncthreads();
    if (w == 0) {
        float2 a = sm[0][lane], b2 = sm[1][lane], c = sm[2][lane], d = sm[3][lane];
        m.x = fmaxf(fmaxf(a.x, b2.x), fmaxf(c.x, d.x));
        m.y = fmaxf(fmaxf(a.y, b2.y), fmaxf(c.y, d.y));
        float2 wf = ((const float2*)Wf)[lane];
        float val = m.x * wf.x + m.y * wf.y;
        #pragma unroll
        for (int off = 32; off; off >>= 1) val += __shfl_xor(val, off);
        if (lane == 0) out[g] = val + bf[0];
    }
}

// ---------------- launch ----------------
extern "C" void kernel_launch(void* const* d_in, const int* in_sizes, int n_in,
                              void* d_out, int out_size, void* d_ws, size_t ws_size,
                              hipStream_t stream) {
    const int*   x    = (const int*)d_in[0];
    const int*   ei   = (const int*)d_in[1];   // [2, E]: src row then dst row
    const int*   batch= (const int*)d_in[2];
    const float* emb  = (const float*)d_in[3];
    const float* W1   = (const float*)d_in[4];
    const float* b1   = (const float*)d_in[5];
    const float* W2   = (const float*)d_in[6];
    const float* b2   = (const float*)d_in[7];
    const float* W3   = (const float*)d_in[8];
    const float* b3   = (const float*)d_in[9];
    const float* Wf   = (const float*)d_in[10];
    const float* bf   = (const float*)d_in[11];
    float* out = (float*)d_out;

    const int* src = ei;
    const int* dst = ei + N_EDGES;

    // workspace layout — hAb (bf16 chain) aliases hA (fp32, written only by
    // layer-3 agg after the last hAb read). 128 rows of slack for gemm tiles.
    char* p = (char*)d_ws;
    float*          hA   = (float*)p;          p += (size_t)(N_NODES + 128) * D * 4; // 51.3 MB
    unsigned short* hAb  = (unsigned short*)hA;                                      // alias
    unsigned short* hwb  = (unsigned short*)p; p += (size_t)(N_NODES + 128) * D * 2; // 25.7 MB
    float* dinv     = (float*)p;            p += (size_t)N_NODES * 4;
    int*   deg_cnt  = (int*)p;              p += (size_t)N_NODES * 4;
    int*   gend     = (int*)p;              p += (size_t)N_GRAPHS * 4;
    int*   gstart   = (int*)p;              p += (size_t)N_GRAPHS * 4;
    int*   row_off  = (int*)p;              p += (size_t)(N_NODES + 4) * 4;
    int*   rank     = (int*)p;              p += (size_t)N_EDGES * 4;               // 6.4 MB
    int2*  csr      = (int2*)p;             p += (size_t)N_EDGES * 8;               // 12.8 MB
    int*   bsum     = (int*)p;              p += 512;

    // zero deg_cnt + gend (contiguous); gstart -> large sentinel
    hipMemsetAsync(deg_cnt, 0, (size_t)(N_NODES + N_GRAPHS) * 4, stream);
    hipMemsetAsync(gstart, 0x7f, (size_t)N_GRAPHS * 4, stream);

    const int EB = (N_EDGES + 255) / 256;    // 6250
    const int NB = (N_NODES + 255) / 256;    // 391
    const int NW = (N_NODES + 3) / 4;        // 25000
    const int GB = (N_NODES + 127) / 128;    // 782

    k_deg  <<<EB, 256, 0, stream>>>(dst, deg_cnt, rank);
    k_scan1<<<SCAN_BLOCKS, 256, 0, stream>>>(deg_cnt, row_off, bsum, dinv);
    k_scan2<<<1, 128, 0, stream>>>(bsum);
    k_scan3<<<SCAN_BLOCKS, 256, 0, stream>>>(row_off, bsum);
    k_fill <<<EB, 256, 0, stream>>>(src, dst, row_off, rank, dinv, csr);
    k_embed<<<NW, 256, 0, stream>>>(x, emb, hAb);

    // layer 1
    k_gemm  <<<GB, 256, 0, stream>>>(hAb, W1, hwb);
    k_agg<1><<<NW, 256, 0, stream>>>(hwb, hAb, row_off, csr, dinv, b1);
    // layer 2
    k_gemm  <<<GB, 256, 0, stream>>>(hAb, W2, hwb);
    k_agg<1><<<NW, 256, 0, stream>>>(hwb, hAb, row_off, csr, dinv, b2);
    // layer 3
    k_gemm  <<<GB, 256, 0, stream>>>(hAb, W3, hwb);
    k_agg<0><<<NW, 256, 0, stream>>>(hwb, hA, row_off, csr, dinv, b3);

    k_bounds<<<NB, 256, 0, stream>>>(batch, gstart, gend);
    k_pool  <<<N_GRAPHS, 256, 0, stream>>>(hA, gstart, gend, Wf, bf, out);
}